// Round 1
// baseline (583.899 us; speedup 1.0000x reference)
//
#include <hip/hip_runtime.h>

#define NN 100000
#define KK 16
#define DD 128
#define DEE 32
#define DTT 32
#define C1 192        // D + DE + DT
#define BN 32         // nodes per block
#define APAD 196      // agg row stride (floats), 196*4 bytes = 16B aligned
#define HPAD 132      // h row stride (floats)

__device__ __forceinline__ void fma4x4(float4& acc, const float4 a,
                                       const float4 w0, const float4 w1,
                                       const float4 w2, const float4 w3) {
  acc.x = fmaf(a.x, w0.x, acc.x);
  acc.x = fmaf(a.y, w1.x, acc.x);
  acc.x = fmaf(a.z, w2.x, acc.x);
  acc.x = fmaf(a.w, w3.x, acc.x);
  acc.y = fmaf(a.x, w0.y, acc.y);
  acc.y = fmaf(a.y, w1.y, acc.y);
  acc.y = fmaf(a.z, w2.y, acc.y);
  acc.y = fmaf(a.w, w3.y, acc.y);
  acc.z = fmaf(a.x, w0.z, acc.z);
  acc.z = fmaf(a.y, w1.z, acc.z);
  acc.z = fmaf(a.z, w2.z, acc.z);
  acc.z = fmaf(a.w, w3.z, acc.z);
  acc.w = fmaf(a.x, w0.w, acc.w);
  acc.w = fmaf(a.y, w1.w, acc.w);
  acc.w = fmaf(a.z, w2.w, acc.w);
  acc.w = fmaf(a.w, w3.w, acc.w);
}

__global__ __launch_bounds__(256, 3) void tgn_layer(
    const float* __restrict__ prev,   // [N, D]   (layer input / gather table)
    const float* __restrict__ edge,   // [N, K, DE] for this layer
    const float* __restrict__ timef,  // [N, K, DT] for this layer
    const float* __restrict__ W1,     // [192, 128]
    const float* __restrict__ b1,     // [128]
    const float* __restrict__ W2,     // [256, 128]
    const float* __restrict__ b2,     // [128]
    const int* __restrict__ idx,      // [N, K]
    float* __restrict__ outp)         // [N, D]
{
  __shared__ float agg[BN][APAD];   // [:,0:192] = [nbr_sum | e_sum | t_sum]; reused for prev tile
  __shared__ float hbuf[BN][HPAD];  // relu(agg@W1+b1)
  __shared__ int   idx_s[BN * KK];

  const int t  = threadIdx.x;
  const int n0 = blockIdx.x * BN;   // NN % BN == 0, no guards needed

  // stage neighbor indices (512 ints)
  for (int i = t; i < BN * KK; i += 256)
    idx_s[i] = idx[(size_t)n0 * KK + i];
  __syncthreads();

  // ---- Phase 1a: neighbor gather-sum -> agg[:, 0:128] ----
  {
    const int d4 = (t & 31) * 4;
    for (int nl = t >> 5; nl < BN; nl += 8) {
      float4 acc = make_float4(0.f, 0.f, 0.f, 0.f);
      #pragma unroll
      for (int j = 0; j < KK; ++j) {
        const int row = idx_s[nl * KK + j];
        const float4 v = *reinterpret_cast<const float4*>(prev + (size_t)row * DD + d4);
        acc.x += v.x; acc.y += v.y; acc.z += v.z; acc.w += v.w;
      }
      *reinterpret_cast<float4*>(&agg[nl][d4]) = acc;
    }
  }

  // ---- Phase 1b: edge/time sums -> agg[:, 128:192] ----
  {
    const int de4 = (t & 7) * 4;
    const int nl  = t >> 3;  // 0..31
    const float* ep = edge  + (size_t)(n0 + nl) * KK * DEE + de4;
    const float* tp = timef + (size_t)(n0 + nl) * KK * DTT + de4;
    float4 ea = make_float4(0.f, 0.f, 0.f, 0.f);
    float4 ta = make_float4(0.f, 0.f, 0.f, 0.f);
    #pragma unroll
    for (int j = 0; j < KK; ++j) {
      const float4 ev = *reinterpret_cast<const float4*>(ep + j * DEE);
      const float4 tv = *reinterpret_cast<const float4*>(tp + j * DTT);
      ea.x += ev.x; ea.y += ev.y; ea.z += ev.z; ea.w += ev.w;
      ta.x += tv.x; ta.y += tv.y; ta.z += tv.z; ta.w += tv.w;
    }
    *reinterpret_cast<float4*>(&agg[nl][DD + de4])        = ea;
    *reinterpret_cast<float4*>(&agg[nl][DD + DEE + de4])  = ta;
  }
  __syncthreads();

  const int d0 = (t & 31) * 4;   // output dim base (0..124)
  const int nb = (t >> 5) * 4;   // node base within tile (0..28)

  // ---- Phase 2: h = relu(agg @ W1 + b1) -> hbuf ----
  {
    float4 acc[4];
    const float4 bias = *reinterpret_cast<const float4*>(b1 + d0);
    #pragma unroll
    for (int i = 0; i < 4; ++i) acc[i] = bias;

    for (int c = 0; c < C1; c += 4) {
      const float4 w0 = *reinterpret_cast<const float4*>(W1 + (size_t)(c + 0) * DD + d0);
      const float4 w1 = *reinterpret_cast<const float4*>(W1 + (size_t)(c + 1) * DD + d0);
      const float4 w2 = *reinterpret_cast<const float4*>(W1 + (size_t)(c + 2) * DD + d0);
      const float4 w3 = *reinterpret_cast<const float4*>(W1 + (size_t)(c + 3) * DD + d0);
      #pragma unroll
      for (int i = 0; i < 4; ++i) {
        const float4 a = *reinterpret_cast<const float4*>(&agg[nb + i][c]);
        fma4x4(acc[i], a, w0, w1, w2, w3);
      }
    }
    #pragma unroll
    for (int i = 0; i < 4; ++i) {
      acc[i].x = fmaxf(acc[i].x, 0.f);
      acc[i].y = fmaxf(acc[i].y, 0.f);
      acc[i].z = fmaxf(acc[i].z, 0.f);
      acc[i].w = fmaxf(acc[i].w, 0.f);
      *reinterpret_cast<float4*>(&hbuf[nb + i][d0]) = acc[i];
    }
  }
  __syncthreads();

  // ---- Phase 3: stage this block's own prev rows into agg[:, 0:128] (reuse) ----
  {
    const int d4 = (t & 31) * 4;
    for (int nl = t >> 5; nl < BN; nl += 8) {
      const float4 v = *reinterpret_cast<const float4*>(prev + (size_t)(n0 + nl) * DD + d4);
      *reinterpret_cast<float4*>(&agg[nl][d4]) = v;
    }
  }
  __syncthreads();

  // ---- Phase 4: out = [prev | h] @ W2 + b2 ----
  {
    float4 acc[4];
    const float4 bias = *reinterpret_cast<const float4*>(b2 + d0);
    #pragma unroll
    for (int i = 0; i < 4; ++i) acc[i] = bias;

    for (int c = 0; c < DD; c += 4) {  // top half of W2, against prev tile
      const float4 w0 = *reinterpret_cast<const float4*>(W2 + (size_t)(c + 0) * DD + d0);
      const float4 w1 = *reinterpret_cast<const float4*>(W2 + (size_t)(c + 1) * DD + d0);
      const float4 w2 = *reinterpret_cast<const float4*>(W2 + (size_t)(c + 2) * DD + d0);
      const float4 w3 = *reinterpret_cast<const float4*>(W2 + (size_t)(c + 3) * DD + d0);
      #pragma unroll
      for (int i = 0; i < 4; ++i) {
        const float4 a = *reinterpret_cast<const float4*>(&agg[nb + i][c]);
        fma4x4(acc[i], a, w0, w1, w2, w3);
      }
    }
    for (int c = 0; c < DD; c += 4) {  // bottom half of W2, against h
      const float4 w0 = *reinterpret_cast<const float4*>(W2 + (size_t)(DD + c + 0) * DD + d0);
      const float4 w1 = *reinterpret_cast<const float4*>(W2 + (size_t)(DD + c + 1) * DD + d0);
      const float4 w2 = *reinterpret_cast<const float4*>(W2 + (size_t)(DD + c + 2) * DD + d0);
      const float4 w3 = *reinterpret_cast<const float4*>(W2 + (size_t)(DD + c + 3) * DD + d0);
      #pragma unroll
      for (int i = 0; i < 4; ++i) {
        const float4 a = *reinterpret_cast<const float4*>(&hbuf[nb + i][c]);
        fma4x4(acc[i], a, w0, w1, w2, w3);
      }
    }
    #pragma unroll
    for (int i = 0; i < 4; ++i) {
      *reinterpret_cast<float4*>(outp + (size_t)(n0 + nb + i) * DD + d0) = acc[i];
    }
  }
}

extern "C" void kernel_launch(void* const* d_in, const int* in_sizes, int n_in,
                              void* d_out, int out_size, void* d_ws, size_t ws_size,
                              hipStream_t stream) {
  const float* features = (const float*)d_in[0];
  const float* edge     = (const float*)d_in[1];
  const float* timef    = (const float*)d_in[2];
  const float* W1       = (const float*)d_in[3];
  const float* b1       = (const float*)d_in[4];
  const float* W2       = (const float*)d_in[5];
  const float* b2       = (const float*)d_in[6];
  const int*   idx      = (const int*)d_in[7];
  float* outp = (float*)d_out;
  float* tmp  = (float*)d_ws;   // layer-1 output ping buffer (N*D floats = 51.2 MB)

  dim3 grid(NN / BN);   // 100000 / 32 = 3125, exact
  dim3 block(256);

  // layer 0: features -> tmp
  tgn_layer<<<grid, block, 0, stream>>>(
      features, edge, timef, W1, b1, W2, b2, idx, tmp);

  // layer 1: tmp -> out
  tgn_layer<<<grid, block, 0, stream>>>(
      tmp,
      edge  + (size_t)NN * KK * DEE,
      timef + (size_t)NN * KK * DTT,
      W1 + (size_t)C1 * DD,
      b1 + DD,
      W2 + (size_t)2 * DD * DD,
      b2 + DD,
      idx + (size_t)NN * KK,
      outp);
}

// Round 2
// 331.732 us; speedup vs baseline: 1.7602x; 1.7602x over previous
//
#include <hip/hip_runtime.h>

#define NN 100000
#define KK 16
#define DD 128
#define DEE 32
#define DTT 32
#define C1 192        // D + DE + DT
#define BN 32         // nodes per block
#define AB 200        // aggb row stride in shorts (192 + 8 pad); 400 B ≡ 4 words mod 32 banks
#define A2B 264       // a2b row stride in shorts (256 + 8 pad); 528 B ≡ 4 words mod 32 banks
#define GRID (NN / BN)

typedef __attribute__((ext_vector_type(8))) short bfrag;    // 8 bf16 = 4 VGPR (MFMA A/B operand)
typedef __attribute__((ext_vector_type(4))) float f32x4;    // MFMA C/D operand
typedef __attribute__((ext_vector_type(4))) short short4v;  // 8-byte LDS/global chunk

__device__ __forceinline__ short f2bf(float x) {  // RNE f32 -> bf16 bits
  unsigned u = __builtin_bit_cast(unsigned, x);
  unsigned r = u + 0x7fffu + ((u >> 16) & 1u);
  return (short)(r >> 16);
}
__device__ __forceinline__ float bf2f(short s) {
  unsigned u = ((unsigned)(unsigned short)s) << 16;
  return __builtin_bit_cast(float, u);
}

// One fused TGN layer. INBF: prev is bf16 (else f32). OUTBF: out is bf16 (else f32).
template<bool INBF, bool OUTBF>
__global__ __launch_bounds__(256, 4) void tgn_mfma(
    const void* __restrict__ prev_,   // [N, D] gather table / layer input
    const float* __restrict__ edge,   // [N, K, DE]
    const float* __restrict__ timef,  // [N, K, DT]
    const float* __restrict__ W1g,    // [192, 128]
    const float* __restrict__ b1g,    // [128]
    const float* __restrict__ W2g,    // [256, 128]
    const float* __restrict__ b2g,    // [128]
    const int* __restrict__ idxg,     // [N, K]
    void* __restrict__ out_)          // [N, D]
{
  __shared__ short aggb[BN][AB];   // bf16 [nbr_sum | e_sum | t_sum], K=192
  __shared__ short a2b[BN][A2B];   // bf16 [prev | h], K=256
  __shared__ int   idx_s[BN * KK];

  const int t  = threadIdx.x;
  const int n0 = blockIdx.x * BN;   // NN % BN == 0

  // stage neighbor indices
  for (int i = t; i < BN * KK; i += 256) idx_s[i] = idxg[(size_t)n0 * KK + i];

  // stage this block's own prev rows -> a2b[:, 0:128] (independent of idx_s)
  {
    const int d4 = (t & 31) * 4;
    for (int nl = t >> 5; nl < BN; nl += 8) {
      short4v o;
      if constexpr (INBF) {
        o = *reinterpret_cast<const short4v*>((const short*)prev_ + (size_t)(n0 + nl) * DD + d4);
      } else {
        const float4 v = *reinterpret_cast<const float4*>((const float*)prev_ + (size_t)(n0 + nl) * DD + d4);
        o[0] = f2bf(v.x); o[1] = f2bf(v.y); o[2] = f2bf(v.z); o[3] = f2bf(v.w);
      }
      *reinterpret_cast<short4v*>(&a2b[nl][d4]) = o;
    }
  }

  // edge/time sums -> aggb[:, 128:192]
  {
    const int c4 = (t & 7) * 4;
    const int nl = t >> 3;  // 0..31
    const float* ep = edge  + (size_t)(n0 + nl) * KK * DEE + c4;
    const float* tp = timef + (size_t)(n0 + nl) * KK * DTT + c4;
    float e0=0,e1=0,e2=0,e3=0, s0=0,s1=0,s2=0,s3=0;
    #pragma unroll
    for (int j = 0; j < KK; ++j) {
      const float4 ev = *reinterpret_cast<const float4*>(ep + j * DEE);
      const float4 tv = *reinterpret_cast<const float4*>(tp + j * DTT);
      e0 += ev.x; e1 += ev.y; e2 += ev.z; e3 += ev.w;
      s0 += tv.x; s1 += tv.y; s2 += tv.z; s3 += tv.w;
    }
    short4v eo; eo[0]=f2bf(e0); eo[1]=f2bf(e1); eo[2]=f2bf(e2); eo[3]=f2bf(e3);
    short4v so; so[0]=f2bf(s0); so[1]=f2bf(s1); so[2]=f2bf(s2); so[3]=f2bf(s3);
    *reinterpret_cast<short4v*>(&aggb[nl][DD + c4])       = eo;
    *reinterpret_cast<short4v*>(&aggb[nl][DD + DEE + c4]) = so;
  }

  __syncthreads();  // idx_s ready

  // neighbor gather-sum -> aggb[:, 0:128]
  {
    const int d4 = (t & 31) * 4;
    for (int nl = t >> 5; nl < BN; nl += 8) {
      float a0=0, a1=0, a2=0, a3=0;
      #pragma unroll
      for (int j = 0; j < KK; ++j) {
        const int row = idx_s[nl * KK + j];
        if constexpr (INBF) {
          const short4v v = *reinterpret_cast<const short4v*>((const short*)prev_ + (size_t)row * DD + d4);
          a0 += bf2f(v[0]); a1 += bf2f(v[1]); a2 += bf2f(v[2]); a3 += bf2f(v[3]);
        } else {
          const float4 v = *reinterpret_cast<const float4*>((const float*)prev_ + (size_t)row * DD + d4);
          a0 += v.x; a1 += v.y; a2 += v.z; a3 += v.w;
        }
      }
      short4v o; o[0]=f2bf(a0); o[1]=f2bf(a1); o[2]=f2bf(a2); o[3]=f2bf(a3);
      *reinterpret_cast<short4v*>(&aggb[nl][d4]) = o;
    }
  }
  __syncthreads();  // aggb ready

  const int lane = t & 63;
  const int wv   = t >> 6;       // wave 0..3
  const int lr   = lane & 15;    // A row / B col / D col
  const int lg   = lane >> 4;    // k-group
  const int n0w  = wv * 32;      // this wave's output-col base

  // ---- GEMM1: h = relu(aggb @ W1 + b1) -> a2b[:, 128:256] ----
  {
    f32x4 acc[2][2];
    #pragma unroll
    for (int nt = 0; nt < 2; ++nt) {
      const float bv = b1g[n0w + nt * 16 + lr];
      acc[0][nt] = (f32x4){bv, bv, bv, bv};
      acc[1][nt] = (f32x4){bv, bv, bv, bv};
    }
    #pragma unroll
    for (int ks = 0; ks < 6; ++ks) {
      const bfrag a0 = *reinterpret_cast<const bfrag*>(&aggb[lr][ks * 32 + lg * 8]);
      const bfrag a1 = *reinterpret_cast<const bfrag*>(&aggb[16 + lr][ks * 32 + lg * 8]);
      const float* wp = W1g + (size_t)(ks * 32 + lg * 8) * DD + n0w + lr;
      bfrag bb0, bb1;
      #pragma unroll
      for (int j = 0; j < 8; ++j) {
        bb0[j] = f2bf(wp[(size_t)j * DD]);
        bb1[j] = f2bf(wp[(size_t)j * DD + 16]);
      }
      acc[0][0] = __builtin_amdgcn_mfma_f32_16x16x32_bf16(a0, bb0, acc[0][0], 0, 0, 0);
      acc[1][0] = __builtin_amdgcn_mfma_f32_16x16x32_bf16(a1, bb0, acc[1][0], 0, 0, 0);
      acc[0][1] = __builtin_amdgcn_mfma_f32_16x16x32_bf16(a0, bb1, acc[0][1], 0, 0, 0);
      acc[1][1] = __builtin_amdgcn_mfma_f32_16x16x32_bf16(a1, bb1, acc[1][1], 0, 0, 0);
    }
    #pragma unroll
    for (int mt = 0; mt < 2; ++mt)
      #pragma unroll
      for (int nt = 0; nt < 2; ++nt)
        #pragma unroll
        for (int r = 0; r < 4; ++r)
          a2b[mt * 16 + lg * 4 + r][DD + n0w + nt * 16 + lr] = f2bf(fmaxf(acc[mt][nt][r], 0.f));
  }
  __syncthreads();  // a2b (prev|h) ready

  // ---- GEMM2: out = a2b @ W2 + b2 ----
  {
    f32x4 acc[2][2];
    #pragma unroll
    for (int nt = 0; nt < 2; ++nt) {
      const float bv = b2g[n0w + nt * 16 + lr];
      acc[0][nt] = (f32x4){bv, bv, bv, bv};
      acc[1][nt] = (f32x4){bv, bv, bv, bv};
    }
    #pragma unroll
    for (int ks = 0; ks < 8; ++ks) {
      const bfrag a0 = *reinterpret_cast<const bfrag*>(&a2b[lr][ks * 32 + lg * 8]);
      const bfrag a1 = *reinterpret_cast<const bfrag*>(&a2b[16 + lr][ks * 32 + lg * 8]);
      const float* wp = W2g + (size_t)(ks * 32 + lg * 8) * DD + n0w + lr;
      bfrag bb0, bb1;
      #pragma unroll
      for (int j = 0; j < 8; ++j) {
        bb0[j] = f2bf(wp[(size_t)j * DD]);
        bb1[j] = f2bf(wp[(size_t)j * DD + 16]);
      }
      acc[0][0] = __builtin_amdgcn_mfma_f32_16x16x32_bf16(a0, bb0, acc[0][0], 0, 0, 0);
      acc[1][0] = __builtin_amdgcn_mfma_f32_16x16x32_bf16(a1, bb0, acc[1][0], 0, 0, 0);
      acc[0][1] = __builtin_amdgcn_mfma_f32_16x16x32_bf16(a0, bb1, acc[0][1], 0, 0, 0);
      acc[1][1] = __builtin_amdgcn_mfma_f32_16x16x32_bf16(a1, bb1, acc[1][1], 0, 0, 0);
    }
    #pragma unroll
    for (int mt = 0; mt < 2; ++mt)
      #pragma unroll
      for (int nt = 0; nt < 2; ++nt)
        #pragma unroll
        for (int r = 0; r < 4; ++r) {
          const float v = acc[mt][nt][r];
          const size_t grow = (size_t)(n0 + mt * 16 + lg * 4 + r);
          const int    gcol = n0w + nt * 16 + lr;
          if constexpr (OUTBF) ((short*)out_)[grow * DD + gcol] = f2bf(v);
          else                 ((float*)out_)[grow * DD + gcol] = v;
        }
  }
}

extern "C" void kernel_launch(void* const* d_in, const int* in_sizes, int n_in,
                              void* d_out, int out_size, void* d_ws, size_t ws_size,
                              hipStream_t stream) {
  const float* features = (const float*)d_in[0];
  const float* edge     = (const float*)d_in[1];
  const float* timef    = (const float*)d_in[2];
  const float* W1       = (const float*)d_in[3];
  const float* b1       = (const float*)d_in[4];
  const float* W2       = (const float*)d_in[5];
  const float* b2       = (const float*)d_in[6];
  const int*   idx      = (const int*)d_in[7];
  float* outp = (float*)d_out;
  short* tmp  = (short*)d_ws;   // layer-1 output as bf16 (N*D*2 = 25.6 MB)

  dim3 grid(GRID);
  dim3 block(256);

  // layer 0: features (f32) -> tmp (bf16)
  tgn_mfma<false, true><<<grid, block, 0, stream>>>(
      features, edge, timef, W1, b1, W2, b2, idx, tmp);

  // layer 1: tmp (bf16) -> out (f32)
  tgn_mfma<true, false><<<grid, block, 0, stream>>>(
      tmp,
      edge  + (size_t)NN * KK * DEE,
      timef + (size_t)NN * KK * DTT,
      W1 + (size_t)C1 * DD,
      b1 + DD,
      W2 + (size_t)2 * DD * DD,
      b2 + DD,
      idx + (size_t)NN * KK,
      outp);
}

// Round 3
// 273.538 us; speedup vs baseline: 2.1346x; 1.2127x over previous
//
#include <hip/hip_runtime.h>

#define NN 100000
#define KK 16
#define DD 128
#define DEE 32
#define DTT 32
#define C1 192        // D + DE + DT
#define BN 32         // nodes per block
#define AB 200        // aggb row stride in shorts (192 + 8 pad)
#define A2B 264       // a2b row stride in shorts (256 + 8 pad)
#define GRID (NN / BN)

// transformed-weight region: per layer, W1T = 24*128*8 = 24576, W2T = 32*128*8 = 32768
#define W1T_SH 24576
#define WLAYER_SH 57344                  // shorts per layer
#define WTOT_SH (2 * WLAYER_SH)          // 114688 shorts = 229376 B
#define TMP_OFF_B 229376                 // tmp (bf16 layer-0 out) byte offset in ws
#define TMP_B (NN * DD * 2)              // 25.6 MB
#define FBF_OFF_B (TMP_OFF_B + TMP_B)
#define FBF_B (NN * DD * 2)

typedef __attribute__((ext_vector_type(8))) short bfrag;    // 8 bf16 = 4 VGPR (MFMA A/B operand)
typedef __attribute__((ext_vector_type(4))) float f32x4;    // MFMA C/D operand
typedef __attribute__((ext_vector_type(4))) short short4v;  // 8-byte chunk

__device__ __forceinline__ short f2bf(float x) {  // RNE f32 -> bf16 bits
  unsigned u = __builtin_bit_cast(unsigned, x);
  unsigned r = u + 0x7fffu + ((u >> 16) & 1u);
  return (short)(r >> 16);
}
__device__ __forceinline__ float bf2f(short s) {
  unsigned u = ((unsigned)(unsigned short)s) << 16;
  return __builtin_bit_cast(float, u);
}

// ---- prep: W1/W2 (both layers) -> bf16 fragment-major [kg][col][8] ----
// out[l*57344 + (kg*128 + col)*8 + j] = W{1,2}[l][kg*8+j][col]
__global__ void prep_weights(const float* __restrict__ W1, const float* __restrict__ W2,
                             short* __restrict__ out) {
  const int t = blockIdx.x * 256 + threadIdx.x;   // grid covers exactly WTOT_SH
  const int l = t / WLAYER_SH;
  const int r = t % WLAYER_SH;
  float v;
  if (r < W1T_SH) {
    const int kg = r >> 10, col = (r >> 3) & 127, j = r & 7;
    v = W1[(size_t)l * C1 * DD + (size_t)(kg * 8 + j) * DD + col];
  } else {
    const int r2 = r - W1T_SH;
    const int kg = r2 >> 10, col = (r2 >> 3) & 127, j = r2 & 7;
    v = W2[(size_t)l * 2 * DD * DD + (size_t)(kg * 8 + j) * DD + col];
  }
  out[t] = f2bf(v);
}

// ---- prep: features f32 -> bf16 table ----
__global__ void feat2bf(const float* __restrict__ f, short* __restrict__ o) {
  const size_t i = ((size_t)blockIdx.x * 256 + threadIdx.x) * 4;
  const float4 v = *reinterpret_cast<const float4*>(f + i);
  short4v s; s[0] = f2bf(v.x); s[1] = f2bf(v.y); s[2] = f2bf(v.z); s[3] = f2bf(v.w);
  *reinterpret_cast<short4v*>(o + i) = s;
}

// One fused TGN layer. INBF: prev is bf16 (else f32). OUTBF: out is bf16 (else f32).
template<bool INBF, bool OUTBF>
__global__ __launch_bounds__(256, 5) void tgn_mfma(
    const void* __restrict__ prev_,   // [N, D] gather table / layer input
    const float* __restrict__ edge,   // [N, K, DE]
    const float* __restrict__ timef,  // [N, K, DT]
    const short* __restrict__ wT,     // this layer's [W1T | W2T] bf16 fragment-major
    const float* __restrict__ b1g,    // [128]
    const float* __restrict__ b2g,    // [128]
    const int* __restrict__ idxg,     // [N, K]
    void* __restrict__ out_)          // [N, D]
{
  __shared__ short aggb[BN][AB];   // bf16 [nbr_sum | e_sum | t_sum], K=192
  __shared__ short a2b[BN][A2B];   // bf16 [prev | h], K=256

  const int t  = threadIdx.x;
  const int n0 = blockIdx.x * BN;   // NN % BN == 0

  // stage this block's own prev rows -> a2b[:, 0:128]
  {
    const int d4 = (t & 31) * 4;
    for (int nl = t >> 5; nl < BN; nl += 8) {
      short4v o;
      if constexpr (INBF) {
        o = *reinterpret_cast<const short4v*>((const short*)prev_ + (size_t)(n0 + nl) * DD + d4);
      } else {
        const float4 v = *reinterpret_cast<const float4*>((const float*)prev_ + (size_t)(n0 + nl) * DD + d4);
        o[0] = f2bf(v.x); o[1] = f2bf(v.y); o[2] = f2bf(v.z); o[3] = f2bf(v.w);
      }
      *reinterpret_cast<short4v*>(&a2b[nl][d4]) = o;
    }
  }

  // edge/time sums -> aggb[:, 128:192]
  {
    const int c4 = (t & 7) * 4;
    const int nl = t >> 3;  // 0..31
    const float* ep = edge  + (size_t)(n0 + nl) * KK * DEE + c4;
    const float* tp = timef + (size_t)(n0 + nl) * KK * DTT + c4;
    float e0=0,e1=0,e2=0,e3=0, s0=0,s1=0,s2=0,s3=0;
    #pragma unroll
    for (int j = 0; j < KK; ++j) {
      const float4 ev = *reinterpret_cast<const float4*>(ep + j * DEE);
      const float4 tv = *reinterpret_cast<const float4*>(tp + j * DTT);
      e0 += ev.x; e1 += ev.y; e2 += ev.z; e3 += ev.w;
      s0 += tv.x; s1 += tv.y; s2 += tv.z; s3 += tv.w;
    }
    short4v eo; eo[0]=f2bf(e0); eo[1]=f2bf(e1); eo[2]=f2bf(e2); eo[3]=f2bf(e3);
    short4v so; so[0]=f2bf(s0); so[1]=f2bf(s1); so[2]=f2bf(s2); so[3]=f2bf(s3);
    *reinterpret_cast<short4v*>(&aggb[nl][DD + c4])       = eo;
    *reinterpret_cast<short4v*>(&aggb[nl][DD + DEE + c4]) = so;
  }

  // neighbor gather-sum -> aggb[:, 0:128]  (idx read straight from global, reg-unrolled)
  {
    const int d4 = (t & 31) * 4;
    for (int nl = t >> 5; nl < BN; nl += 8) {
      const int4* ip = reinterpret_cast<const int4*>(idxg + (size_t)(n0 + nl) * KK);
      const int4 i0 = ip[0], i1 = ip[1], i2 = ip[2], i3 = ip[3];
      const int rows[16] = {i0.x, i0.y, i0.z, i0.w, i1.x, i1.y, i1.z, i1.w,
                            i2.x, i2.y, i2.z, i2.w, i3.x, i3.y, i3.z, i3.w};
      float a0=0, a1=0, a2=0, a3=0;
      #pragma unroll
      for (int j = 0; j < 16; ++j) {
        if constexpr (INBF) {
          const short4v v = *reinterpret_cast<const short4v*>((const short*)prev_ + (size_t)rows[j] * DD + d4);
          a0 += bf2f(v[0]); a1 += bf2f(v[1]); a2 += bf2f(v[2]); a3 += bf2f(v[3]);
        } else {
          const float4 v = *reinterpret_cast<const float4*>((const float*)prev_ + (size_t)rows[j] * DD + d4);
          a0 += v.x; a1 += v.y; a2 += v.z; a3 += v.w;
        }
      }
      short4v o; o[0]=f2bf(a0); o[1]=f2bf(a1); o[2]=f2bf(a2); o[3]=f2bf(a3);
      *reinterpret_cast<short4v*>(&aggb[nl][d4]) = o;
    }
  }
  __syncthreads();  // aggb + a2b[:,0:128] ready

  const int lane = t & 63;
  const int wv   = t >> 6;       // wave 0..3
  const int lr   = lane & 15;    // A row / B col / D col
  const int lg   = lane >> 4;    // k-group
  const int n0w  = wv * 32;      // this wave's output-col base

  // ---- GEMM1: h = relu(aggb @ W1 + b1) -> a2b[:, 128:256] ----
  {
    f32x4 acc[2][2];
    #pragma unroll
    for (int nt = 0; nt < 2; ++nt) {
      const float bv = b1g[n0w + nt * 16 + lr];
      acc[0][nt] = (f32x4){bv, bv, bv, bv};
      acc[1][nt] = (f32x4){bv, bv, bv, bv};
    }
    #pragma unroll
    for (int ks = 0; ks < 6; ++ks) {
      const bfrag a0 = *reinterpret_cast<const bfrag*>(&aggb[lr][ks * 32 + lg * 8]);
      const bfrag a1 = *reinterpret_cast<const bfrag*>(&aggb[16 + lr][ks * 32 + lg * 8]);
      const short* wp = wT + ((size_t)((ks * 4 + lg) * 128) + n0w + lr) * 8;
      const bfrag bb0 = *reinterpret_cast<const bfrag*>(wp);
      const bfrag bb1 = *reinterpret_cast<const bfrag*>(wp + 16 * 8);
      acc[0][0] = __builtin_amdgcn_mfma_f32_16x16x32_bf16(a0, bb0, acc[0][0], 0, 0, 0);
      acc[1][0] = __builtin_amdgcn_mfma_f32_16x16x32_bf16(a1, bb0, acc[1][0], 0, 0, 0);
      acc[0][1] = __builtin_amdgcn_mfma_f32_16x16x32_bf16(a0, bb1, acc[0][1], 0, 0, 0);
      acc[1][1] = __builtin_amdgcn_mfma_f32_16x16x32_bf16(a1, bb1, acc[1][1], 0, 0, 0);
    }
    #pragma unroll
    for (int mt = 0; mt < 2; ++mt)
      #pragma unroll
      for (int nt = 0; nt < 2; ++nt)
        #pragma unroll
        for (int r = 0; r < 4; ++r)
          a2b[mt * 16 + lg * 4 + r][DD + n0w + nt * 16 + lr] = f2bf(fmaxf(acc[mt][nt][r], 0.f));
  }
  __syncthreads();  // a2b (prev|h) ready

  // ---- GEMM2: out = a2b @ W2 + b2 ----
  {
    const short* w2T = wT + W1T_SH;
    f32x4 acc[2][2];
    #pragma unroll
    for (int nt = 0; nt < 2; ++nt) {
      const float bv = b2g[n0w + nt * 16 + lr];
      acc[0][nt] = (f32x4){bv, bv, bv, bv};
      acc[1][nt] = (f32x4){bv, bv, bv, bv};
    }
    #pragma unroll
    for (int ks = 0; ks < 8; ++ks) {
      const bfrag a0 = *reinterpret_cast<const bfrag*>(&a2b[lr][ks * 32 + lg * 8]);
      const bfrag a1 = *reinterpret_cast<const bfrag*>(&a2b[16 + lr][ks * 32 + lg * 8]);
      const short* wp = w2T + ((size_t)((ks * 4 + lg) * 128) + n0w + lr) * 8;
      const bfrag bb0 = *reinterpret_cast<const bfrag*>(wp);
      const bfrag bb1 = *reinterpret_cast<const bfrag*>(wp + 16 * 8);
      acc[0][0] = __builtin_amdgcn_mfma_f32_16x16x32_bf16(a0, bb0, acc[0][0], 0, 0, 0);
      acc[1][0] = __builtin_amdgcn_mfma_f32_16x16x32_bf16(a1, bb0, acc[1][0], 0, 0, 0);
      acc[0][1] = __builtin_amdgcn_mfma_f32_16x16x32_bf16(a0, bb1, acc[0][1], 0, 0, 0);
      acc[1][1] = __builtin_amdgcn_mfma_f32_16x16x32_bf16(a1, bb1, acc[1][1], 0, 0, 0);
    }
    #pragma unroll
    for (int mt = 0; mt < 2; ++mt)
      #pragma unroll
      for (int nt = 0; nt < 2; ++nt)
        #pragma unroll
        for (int r = 0; r < 4; ++r) {
          const float v = acc[mt][nt][r];
          const size_t grow = (size_t)(n0 + mt * 16 + lg * 4 + r);
          const int    gcol = n0w + nt * 16 + lr;
          if constexpr (OUTBF) ((short*)out_)[grow * DD + gcol] = f2bf(v);
          else                 ((float*)out_)[grow * DD + gcol] = v;
        }
  }
}

extern "C" void kernel_launch(void* const* d_in, const int* in_sizes, int n_in,
                              void* d_out, int out_size, void* d_ws, size_t ws_size,
                              hipStream_t stream) {
  const float* features = (const float*)d_in[0];
  const float* edge     = (const float*)d_in[1];
  const float* timef    = (const float*)d_in[2];
  const float* W1       = (const float*)d_in[3];
  const float* b1       = (const float*)d_in[4];
  const float* W2       = (const float*)d_in[5];
  const float* b2       = (const float*)d_in[6];
  const int*   idx      = (const int*)d_in[7];
  float* outp = (float*)d_out;

  short* wT     = (short*)d_ws;                            // 229 KB transformed weights
  short* tmp    = (short*)((char*)d_ws + TMP_OFF_B);       // 25.6 MB bf16 layer-0 out
  short* featbf = (short*)((char*)d_ws + FBF_OFF_B);       // 25.6 MB bf16 features
  const bool use_fbf = ws_size >= (size_t)FBF_OFF_B + FBF_B;

  dim3 block(256);

  prep_weights<<<dim3(WTOT_SH / 256), block, 0, stream>>>(W1, W2, wT);
  if (use_fbf)
    feat2bf<<<dim3(NN * DD / 4 / 256), block, 0, stream>>>(features, featbf);

  // layer 0 -> tmp (bf16)
  if (use_fbf)
    tgn_mfma<true, true><<<dim3(GRID), block, 0, stream>>>(
        featbf, edge, timef, wT, b1, b2, idx, tmp);
  else
    tgn_mfma<false, true><<<dim3(GRID), block, 0, stream>>>(
        features, edge, timef, wT, b1, b2, idx, tmp);

  // layer 1 -> out (f32)
  tgn_mfma<true, false><<<dim3(GRID), block, 0, stream>>>(
      tmp,
      edge  + (size_t)NN * KK * DEE,
      timef + (size_t)NN * KK * DTT,
      wT + WLAYER_SH,
      b1 + DD,
      b2 + DD,
      idx + (size_t)NN * KK,
      outp);
}